// Round 8
// baseline (385.096 us; speedup 1.0000x reference)
//
#include <hip/hip_runtime.h>

#define HEADS 4
#define OUTC 64
#define INC 128
#define HC 256   // HEADS*OUTC
#define NEG 0.2f

typedef __attribute__((ext_vector_type(8))) short bf16x8;
typedef __attribute__((ext_vector_type(4))) float f32x4;

static __device__ __forceinline__ float bf2f(unsigned short u){
  unsigned int x = ((unsigned int)u) << 16;
  return __uint_as_float(x);
}
static __device__ __forceinline__ unsigned short f2bf(float f){
  unsigned int x = __float_as_uint(f);
  unsigned int lsb = (x >> 16) & 1u;
  x += 0x7fffu + lsb;           // RNE
  return (unsigned short)(x >> 16);
}
static __device__ __forceinline__ void split8(float4 a, float4 b, bf16x8& hi, bf16x8& lo){
  float v[8] = {a.x, a.y, a.z, a.w, b.x, b.y, b.z, b.w};
  #pragma unroll
  for (int i = 0; i < 8; ++i){
    unsigned short h = f2bf(v[i]);
    hi[i] = (short)h;
    lo[i] = (short)f2bf(v[i] - bf2f(h));
  }
}

#define SPLITB 128   // (INC*HC)/256 work items for W-split
#define GRID 512     // 2 blocks/CU x 256 CUs -> all co-resident (barrier-safe)

// software global barrier: monotonic counter, device-scope atomics.
// Safe because all GRID blocks are co-resident (512 = 2/CU, LDS 11.5KB, VGPR<=256).
static __device__ __forceinline__ void gbar(int* cnt, int target){
  __syncthreads();
  if (threadIdx.x == 0){
    __threadfence();                       // release: prior stores visible device-wide
    atomicAdd(cnt, 1);
    while (atomicAdd(cnt, 0) < target){ __builtin_amdgcn_s_sleep(2); }
  }
  __syncthreads();
  __threadfence();                         // acquire: refresh L1 view for all threads
}

// ---- mega-kernel: [A] Wsplit+edgehist | bar | [B] scan+GEMM | bar | [C] scatter ----
__global__ __launch_bounds__(256, 2) void k_mega(const float* __restrict__ X,
    const float* __restrict__ W, unsigned short* __restrict__ Wthi,
    unsigned short* __restrict__ Wtlo, const float* __restrict__ att_src,
    const float* __restrict__ att_dst, unsigned short* __restrict__ XPh,
    float* __restrict__ a_src, float* __restrict__ a_dst,
    const int* __restrict__ ei, int* __restrict__ srcc, int* __restrict__ dstc,
    int* __restrict__ pos, int* __restrict__ deg, int* __restrict__ rowstart,
    int* __restrict__ bsum, int* __restrict__ csr, int* __restrict__ cnt,
    int N, int E, int GB, int EB, int nb){
  __shared__ unsigned short shi[64][40];
  __shared__ unsigned short slo[64][40];
  __shared__ int tsum[256];
  __shared__ int bps[65];

  // ===== phase A: W split+transpose | edge canonicalize + degree histogram =====
  for (int it = blockIdx.x; it < SPLITB + EB; it += GRID){
    if (it < SPLITB){
      int t = it * 256 + threadIdx.x;            // 0..32767
      int k = t >> 8, n = t & 255;
      float v = W[t];
      unsigned short hi = f2bf(v);
      Wthi[n * INC + k] = hi;
      Wtlo[n * INC + k] = f2bf(v - bf2f(hi));
    } else {
      int e = (it - SPLITB) * 256 + threadIdx.x;
      bool valid = (e < E);
      int ee = valid ? e : 0;
      int hiw = ei[2 * ee + 1];
      bool hz = valid ? (hiw == 0) : true;
      unsigned long long mask = __ballot(hz);
      bool i64 = (mask == ~0ULL);
      int s, d;
      if (i64){ s = ei[2 * ee]; d = ei[2 * (size_t)E + 2 * ee]; }
      else    { s = ei[ee];     d = ei[(size_t)E + ee]; }
      if (valid){
        srcc[e] = s; dstc[e] = d;
        pos[e] = atomicAdd(&deg[d], 1);
      }
    }
  }
  gbar(cnt, GRID);

  // ===== phase B: deg chunk-scan (items [0,nb)) | GEMM (items [nb,nb+GB)) =====
  for (int it = blockIdx.x; it < nb + GB; it += GRID){
    if (it < nb){
      // ---- scan chunk sb: local exclusive scan of 1024 deg entries ----
      int sb = it;
      int t = threadIdx.x;
      int base = sb * 1024 + t * 4;
      int v[4]; int s = 0;
      #pragma unroll
      for (int k = 0; k < 4; ++k){ int i = base + k; v[k] = (i < N) ? deg[i] : 0; s += v[k]; }
      tsum[t] = s;
      __syncthreads();
      for (int off = 1; off < 256; off <<= 1){
        int x = (t >= off) ? tsum[t - off] : 0;
        __syncthreads();
        tsum[t] += x;
        __syncthreads();
      }
      int excl = tsum[t] - s;
      if (t == 255){
        bsum[sb] = tsum[255];
        if (sb == nb - 1) rowstart[N] = tsum[255];
      }
      int run = excl;
      #pragma unroll
      for (int k = 0; k < 4; ++k){ int i = base + k; if (i < N) rowstart[i] = run; run += v[k]; }
      __syncthreads();
    } else {
      // ---- GEMM block: 64 rows x 256 cols; wave w = head w ----
      int gi = it - nb;
      int w = threadIdx.x >> 6, lane = threadIdx.x & 63;
      int m0 = gi * 64;
      int quad = lane >> 4;
      int l15 = lane & 15;
      int colg[4];
      #pragma unroll
      for (int t = 0; t < 4; ++t) colg[t] = w * 64 + t * 16 + l15;
      bool rv[4];
      #pragma unroll
      for (int rt = 0; rt < 4; ++rt) rv[rt] = (m0 + rt * 16) < N;  // N%16==0
      int myrow = rv[w] ? (m0 + w * 16 + l15) : 0;

      f32x4 acc[4][4];
      #pragma unroll
      for (int rt = 0; rt < 4; ++rt)
        #pragma unroll
        for (int t = 0; t < 4; ++t) acc[rt][t] = (f32x4){0.f, 0.f, 0.f, 0.f};

      #pragma unroll
      for (int kk = 0; kk < 4; ++kk){
        const float* xr = X + (size_t)myrow * INC + kk * 32 + quad * 8;
        float4 va = *(const float4*)xr;
        float4 vb = *(const float4*)(xr + 4);
        bf16x8 bh[4], bl[4];
        #pragma unroll
        for (int t = 0; t < 4; ++t){
          size_t bo = (size_t)colg[t] * INC + kk * 32 + quad * 8;
          bh[t] = *(const bf16x8*)(Wthi + bo);
          bl[t] = *(const bf16x8*)(Wtlo + bo);
        }
        bf16x8 ah1, al1;
        split8(va, vb, ah1, al1);
        __syncthreads();                         // protect LDS (prev k-step / prev item)
        *(bf16x8*)&shi[w * 16 + l15][quad * 8] = ah1;
        *(bf16x8*)&slo[w * 16 + l15][quad * 8] = al1;
        __syncthreads();
        bf16x8 ah[4], al[4];
        #pragma unroll
        for (int rt = 0; rt < 4; ++rt){
          ah[rt] = *(const bf16x8*)&shi[rt * 16 + l15][quad * 8];
          al[rt] = *(const bf16x8*)&slo[rt * 16 + l15][quad * 8];
        }
        #pragma unroll
        for (int rt = 0; rt < 4; ++rt){
          #pragma unroll
          for (int t = 0; t < 4; ++t){
            acc[rt][t] = __builtin_amdgcn_mfma_f32_16x16x32_bf16(ah[rt], bh[t], acc[rt][t], 0, 0, 0);
            acc[rt][t] = __builtin_amdgcn_mfma_f32_16x16x32_bf16(ah[rt], bl[t], acc[rt][t], 0, 0, 0);
            acc[rt][t] = __builtin_amdgcn_mfma_f32_16x16x32_bf16(al[rt], bh[t], acc[rt][t], 0, 0, 0);
          }
        }
      }

      // store XPh (bf16). C/D layout: col=l15, row=quad*4+r
      #pragma unroll
      for (int rt = 0; rt < 4; ++rt){
        if (!rv[rt]) continue;
        #pragma unroll
        for (int t = 0; t < 4; ++t){
          #pragma unroll
          for (int r = 0; r < 4; ++r){
            XPh[(size_t)(m0 + rt * 16 + quad * 4 + r) * HC + colg[t]] = f2bf(acc[rt][t][r]);
          }
        }
      }

      // logits epilogue
      float as[4], ad[4];
      #pragma unroll
      for (int t = 0; t < 4; ++t){
        as[t] = att_src[colg[t]];
        ad[t] = att_dst[colg[t]];
      }
      #pragma unroll
      for (int rt = 0; rt < 4; ++rt){
        if (!rv[rt]) continue;
        float ps[4], pd[4];
        #pragma unroll
        for (int r = 0; r < 4; ++r){
          ps[r] = acc[rt][0][r] * as[0] + acc[rt][1][r] * as[1]
                + acc[rt][2][r] * as[2] + acc[rt][3][r] * as[3];
          pd[r] = acc[rt][0][r] * ad[0] + acc[rt][1][r] * ad[1]
                + acc[rt][2][r] * ad[2] + acc[rt][3][r] * ad[3];
        }
        #pragma unroll
        for (int msk = 1; msk < 16; msk <<= 1){
          #pragma unroll
          for (int r = 0; r < 4; ++r){
            ps[r] += __shfl_xor(ps[r], msk, 64);
            pd[r] += __shfl_xor(pd[r], msk, 64);
          }
        }
        if (l15 == 0){
          #pragma unroll
          for (int r = 0; r < 4; ++r){
            int n = m0 + rt * 16 + quad * 4 + r;
            a_src[n * HEADS + w] = ps[r];
            a_dst[n * HEADS + w] = pd[r];
          }
        }
      }
    }
  }
  gbar(cnt, 2 * GRID);

  // ===== phase C: scatter (reconstruct cross-chunk prefix from bsum) =====
  {
    int t = threadIdx.x;
    if (t < 64){
      int v = (t < nb) ? bsum[t] : 0;
      #pragma unroll
      for (int off = 1; off < 64; off <<= 1){
        int u = __shfl_up(v, off, 64);
        if (t >= off) v += u;
      }
      bps[t + 1] = v;
      if (t == 0) bps[0] = 0;
    }
    __syncthreads();
    for (int it = blockIdx.x; it < EB; it += GRID){
      int e = it * 256 + t;
      if (e < E){
        int d = dstc[e];
        csr[rowstart[d] + bps[d >> 10] + pos[e]] = srcc[e];
      }
    }
  }
}

// ---- fused softmax-coef + gather: wave = node (all 4 heads) ----
__global__ __launch_bounds__(256) void k_fused(const unsigned short* __restrict__ XPh,
    const float* __restrict__ a_src, const float* __restrict__ a_dst,
    const int* __restrict__ rowstart, const int* __restrict__ bsum,
    const int* __restrict__ csr, const float* __restrict__ bias,
    float* __restrict__ out, int N, int nb){
  __shared__ float sh[4][64][4];               // [wave][slot][head]
  __shared__ int bps[65];
  int w = threadIdx.x >> 6, lane = threadIdx.x & 63;
  if (threadIdx.x < 64){
    int v = (threadIdx.x < nb) ? bsum[threadIdx.x] : 0;
    #pragma unroll
    for (int off = 1; off < 64; off <<= 1){
      int u = __shfl_up(v, off, 64);
      if (threadIdx.x >= off) v += u;
    }
    bps[threadIdx.x + 1] = v;
    if (threadIdx.x == 0) bps[0] = 0;
  }
  __syncthreads();

  int n = blockIdx.x * 4 + w;
  bool alive = (n < N);
  if (!alive) n = 0;
  int r0 = rowstart[n] + bps[n >> 10];
  int r1 = rowstart[n + 1] + bps[(n + 1) >> 10];
  int deg = r1 - r0;
  int total = deg + 1;
  int h = lane >> 4;
  float4 ad4 = *(const float4*)&a_dst[n * HEADS];
  bool fast = (total <= 64);
  int jv = n;
  float msel = 0.f, inv_sel = 0.f;

  if (fast){
    if (lane < deg) jv = csr[r0 + lane];
    float l0 = -1e30f, l1 = -1e30f, l2 = -1e30f, l3 = -1e30f;
    if (lane < total){
      float4 a4 = *(const float4*)&a_src[jv * HEADS];
      l0 = a4.x + ad4.x; l0 = (l0 > 0.f) ? l0 : NEG * l0;
      l1 = a4.y + ad4.y; l1 = (l1 > 0.f) ? l1 : NEG * l1;
      l2 = a4.z + ad4.z; l2 = (l2 > 0.f) ? l2 : NEG * l2;
      l3 = a4.w + ad4.w; l3 = (l3 > 0.f) ? l3 : NEG * l3;
    }
    float p0 = __expf(l0), p1 = __expf(l1), p2 = __expf(l2), p3 = __expf(l3);
    float s0 = p0, s1 = p1, s2 = p2, s3 = p3;
    #pragma unroll
    for (int msk = 32; msk; msk >>= 1){
      s0 += __shfl_xor(s0, msk, 64);
      s1 += __shfl_xor(s1, msk, 64);
      s2 += __shfl_xor(s2, msk, 64);
      s3 += __shfl_xor(s3, msk, 64);
    }
    if (lane < total){
      sh[w][lane][0] = p0 / s0;
      sh[w][lane][1] = p1 / s1;
      sh[w][lane][2] = p2 / s2;
      sh[w][lane][3] = p3 / s3;
    }
  } else {
    float m[4] = {-1e30f, -1e30f, -1e30f, -1e30f};
    float s[4] = {0.f, 0.f, 0.f, 0.f};
    float adArr[4] = {ad4.x, ad4.y, ad4.z, ad4.w};
    for (int e = lane; e < total; e += 64){
      int j = (e < deg) ? csr[r0 + e] : n;
      float4 a4 = *(const float4*)&a_src[j * HEADS];
      float aa[4] = {a4.x, a4.y, a4.z, a4.w};
      #pragma unroll
      for (int hh = 0; hh < 4; ++hh){
        float l = aa[hh] + adArr[hh];
        l = (l > 0.f) ? l : NEG * l;
        if (l > m[hh]){ s[hh] = s[hh] * __expf(m[hh] - l) + 1.f; m[hh] = l; }
        else            s[hh] += __expf(l - m[hh]);
      }
    }
    #pragma unroll
    for (int hh = 0; hh < 4; ++hh){
      float mm = m[hh], ss = s[hh];
      #pragma unroll
      for (int msk = 32; msk; msk >>= 1){
        float m2 = __shfl_xor(mm, msk, 64);
        float s2 = __shfl_xor(ss, msk, 64);
        float M = fmaxf(mm, m2);
        float ns = 0.f;
        if (mm > -1e29f) ns += ss * __expf(mm - M);
        if (m2 > -1e29f) ns += s2 * __expf(m2 - M);
        mm = M; ss = ns;
      }
      m[hh] = mm; s[hh] = ss;
    }
    msel    = (h == 0) ? m[0] : (h == 1) ? m[1] : (h == 2) ? m[2] : m[3];
    inv_sel = 1.f / ((h == 0) ? s[0] : (h == 1) ? s[1] : (h == 2) ? s[2] : s[3]);
  }

  float a0 = 0.f, a1 = 0.f, a2 = 0.f, a3 = 0.f;
  const unsigned short* xb = XPh + lane * 4;
  if (fast){
    int e = 0;
    for (; e + 8 <= total; e += 8){
      int jj[8]; float cf[8]; ushort4 xv[8];
      #pragma unroll
      for (int q = 0; q < 8; ++q){
        jj[q] = __builtin_amdgcn_readlane(jv, e + q);
        cf[q] = sh[w][e + q][h];
      }
      #pragma unroll
      for (int q = 0; q < 8; ++q) xv[q] = *(const ushort4*)(xb + (size_t)jj[q] * HC);
      #pragma unroll
      for (int q = 0; q < 8; ++q){
        a0 += cf[q] * bf2f(xv[q].x); a1 += cf[q] * bf2f(xv[q].y);
        a2 += cf[q] * bf2f(xv[q].z); a3 += cf[q] * bf2f(xv[q].w);
      }
    }
    for (; e < total; ++e){
      int j = __builtin_amdgcn_readlane(jv, e);
      float c = sh[w][e][h];
      ushort4 xv = *(const ushort4*)(xb + (size_t)j * HC);
      a0 += c * bf2f(xv.x); a1 += c * bf2f(xv.y); a2 += c * bf2f(xv.z); a3 += c * bf2f(xv.w);
    }
  } else {
    float adh = (h == 0) ? ad4.x : (h == 1) ? ad4.y : (h == 2) ? ad4.z : ad4.w;
    for (int e = 0; e < total; ++e){
      int j = (e < deg) ? csr[r0 + e] : n;
      float4 a4 = *(const float4*)&a_src[j * HEADS];
      float ah = (h == 0) ? a4.x : (h == 1) ? a4.y : (h == 2) ? a4.z : a4.w;
      float l = ah + adh;
      l = (l > 0.f) ? l : NEG * l;
      float c = __expf(l - msel) * inv_sel;
      ushort4 xv = *(const ushort4*)(xb + (size_t)j * HC);
      a0 += c * bf2f(xv.x); a1 += c * bf2f(xv.y); a2 += c * bf2f(xv.z); a3 += c * bf2f(xv.w);
    }
  }
  if (alive){
    float4 b4 = *(const float4*)&bias[lane * 4];
    f32x4 r;
    r[0] = a0 + b4.x; r[1] = a1 + b4.y; r[2] = a2 + b4.z; r[3] = a3 + b4.w;
    __builtin_nontemporal_store(r, (f32x4*)&out[(size_t)n * HC + lane * 4]);
  }
}

extern "C" void kernel_launch(void* const* d_in, const int* in_sizes, int n_in,
                              void* d_out, int out_size, void* d_ws, size_t ws_size,
                              hipStream_t stream){
  const float* x       = (const float*)d_in[0];
  const float* W       = (const float*)d_in[1];
  const float* att_src = (const float*)d_in[2];
  const float* att_dst = (const float*)d_in[3];
  const float* bias    = (const float*)d_in[4];
  const int*   ei      = (const int*)d_in[5];
  int N = in_sizes[0] / INC;     // 50000
  int E = in_sizes[5] / 2;       // 800000

  char* p = (char*)d_ws;
  auto alloc = [&](size_t bytes)->char*{
    char* r = p; p += (bytes + 255) & ~(size_t)255; return r;
  };
  unsigned short* Wthi = (unsigned short*)alloc((size_t)INC * HC * 2);
  unsigned short* Wtlo = (unsigned short*)alloc((size_t)INC * HC * 2);
  unsigned short* XPh  = (unsigned short*)alloc((size_t)N * HC * 2);
  float* aSrc          = (float*)alloc((size_t)N * HEADS * 4);
  float* aDst          = (float*)alloc((size_t)N * HEADS * 4);
  int* cnt             = (int*)alloc(256);              // barrier counter
  int* deg             = (int*)alloc((size_t)N * 4);    // contiguous after cnt
  int* rowstart        = (int*)alloc(((size_t)N + 1) * 4);
  int* srcc            = (int*)alloc((size_t)E * 4);
  int* dstc            = (int*)alloc((size_t)E * 4);
  int* pos             = (int*)alloc((size_t)E * 4);
  int* csr             = (int*)alloc((size_t)E * 4);
  int* bsum            = (int*)alloc(256 * 4);

  int GB = (N + 63) / 64;        // 782 gemm items
  int EB = (E + 255) / 256;      // 3125 edge items
  int nb = (N + 1023) / 1024;    // 49 scan chunks

  // one memset zeroes barrier counter + deg (contiguous in ws)
  hipMemsetAsync(cnt, 0, 256 + (size_t)N * 4, stream);

  k_mega<<<GRID, 256, 0, stream>>>(x, W, Wthi, Wtlo, att_src, att_dst,
                                   XPh, aSrc, aDst, ei, srcc, dstc, pos, deg,
                                   rowstart, bsum, csr, cnt, N, E, GB, EB, nb);

  k_fused<<<(N + 3) / 4, 256, 0, stream>>>(XPh, aSrc, aDst, rowstart, bsum, csr,
                                           bias, (float*)d_out, N, nb);
}

// Round 9
// 234.493 us; speedup vs baseline: 1.6422x; 1.6422x over previous
//
#include <hip/hip_runtime.h>

#define HEADS 4
#define OUTC 64
#define INC 128
#define HC 256   // HEADS*OUTC
#define NEG 0.2f

typedef __attribute__((ext_vector_type(8))) short bf16x8;
typedef __attribute__((ext_vector_type(4))) float f32x4;

static __device__ __forceinline__ float bf2f(unsigned short u){
  unsigned int x = ((unsigned int)u) << 16;
  return __uint_as_float(x);
}
static __device__ __forceinline__ unsigned short f2bf(float f){
  unsigned int x = __float_as_uint(f);
  unsigned int lsb = (x >> 16) & 1u;
  x += 0x7fffu + lsb;           // RNE
  return (unsigned short)(x >> 16);
}
static __device__ __forceinline__ void split8(float4 a, float4 b, bf16x8& hi, bf16x8& lo){
  float v[8] = {a.x, a.y, a.z, a.w, b.x, b.y, b.z, b.w};
  #pragma unroll
  for (int i = 0; i < 8; ++i){
    unsigned short h = f2bf(v[i]);
    hi[i] = (short)h;
    lo[i] = (short)f2bf(v[i] - bf2f(h));
  }
}

#define SPLITB 128   // (INC*HC)/256 blocks for W-split

// ---- merged: W split+transpose (blocks 0..127) | edge canonicalize + degree hist ----
// (src,dst) packed into one int2 store; pos = arrival order from the deg histogram.
__global__ void k_pre(const float* __restrict__ W, unsigned short* __restrict__ Wthi,
                      unsigned short* __restrict__ Wtlo, const int* __restrict__ ei,
                      int2* __restrict__ sd, int* __restrict__ pos,
                      int* __restrict__ deg, int E){
  if (blockIdx.x < SPLITB){
    int t = blockIdx.x * 256 + threadIdx.x;      // 0..32767
    int k = t >> 8, n = t & 255;
    float v = W[t];
    unsigned short hi = f2bf(v);
    Wthi[n * INC + k] = hi;
    Wtlo[n * INC + k] = f2bf(v - bf2f(hi));
    return;
  }
  int e = (blockIdx.x - SPLITB) * 256 + threadIdx.x;
  bool valid = (e < E);
  int ee = valid ? e : 0;
  int hiw = ei[2 * ee + 1];
  bool hz = valid ? (hiw == 0) : true;
  unsigned long long mask = __ballot(hz);
  bool i64 = (mask == ~0ULL);
  int s, d;
  if (i64){ s = ei[2 * ee]; d = ei[2 * (size_t)E + 2 * ee]; }
  else    { s = ei[ee];     d = ei[(size_t)E + ee]; }
  if (valid){
    sd[e] = make_int2(s, d);
    pos[e] = atomicAdd(&deg[d], 1);
  }
}

// ---- merged: fused GEMM+logits (blocks [0,GB)) | deg chunk-scan (blocks [GB,GB+nb)) ----
// GEMM: block = 64 rows x 256 cols; wave w = head w. Each wave splits only its own
// 16 X rows into LDS; all waves read all 64 rows' fragments (4x less split VALU).
// Scan: per-1024-chunk local exclusive scan of deg -> rowstart(local) + bsum totals.
// Cross-chunk prefix reconstructed by consumers from bsum (49-entry shfl scan).
__global__ __launch_bounds__(256) void k_gemm_scan(const float* __restrict__ X,
    const unsigned short* __restrict__ Wthi, const unsigned short* __restrict__ Wtlo,
    const float* __restrict__ att_src, const float* __restrict__ att_dst,
    unsigned short* __restrict__ XPh, float* __restrict__ a_src, float* __restrict__ a_dst,
    const int* __restrict__ deg, int* __restrict__ rowstart, int* __restrict__ bsum,
    int N, int GB, int nb){
  __shared__ unsigned short shi[64][40];         // 32 cols padded to 40 (>=2-way only)
  __shared__ unsigned short slo[64][40];
  __shared__ int tsum[256];

  if (blockIdx.x >= GB){
    // ---- scan path ----
    int sb = blockIdx.x - GB;
    int t = threadIdx.x;
    int base = sb * 1024 + t * 4;
    int v[4]; int s = 0;
    #pragma unroll
    for (int k = 0; k < 4; ++k){ int i = base + k; v[k] = (i < N) ? deg[i] : 0; s += v[k]; }
    tsum[t] = s;
    __syncthreads();
    for (int off = 1; off < 256; off <<= 1){
      int x = (t >= off) ? tsum[t - off] : 0;
      __syncthreads();
      tsum[t] += x;
      __syncthreads();
    }
    int excl = tsum[t] - s;
    if (t == 255){
      bsum[sb] = tsum[255];
      if (sb == nb - 1) rowstart[N] = tsum[255];   // local-inclusive total of last chunk
    }
    int run = excl;
    #pragma unroll
    for (int k = 0; k < 4; ++k){ int i = base + k; if (i < N) rowstart[i] = run; run += v[k]; }
    return;
  }

  // ---- GEMM path ----
  int w = threadIdx.x >> 6, lane = threadIdx.x & 63;
  int m0 = blockIdx.x * 64;
  int quad = lane >> 4;
  int l15 = lane & 15;
  int colg[4];
  #pragma unroll
  for (int t = 0; t < 4; ++t) colg[t] = w * 64 + t * 16 + l15;

  bool rv[4];
  #pragma unroll
  for (int rt = 0; rt < 4; ++rt) rv[rt] = (m0 + rt * 16) < N;  // N%16==0
  int myrow = rv[w] ? (m0 + w * 16 + l15) : 0;   // the 16 rows THIS wave stages

  f32x4 acc[4][4];                               // [rt][t]
  #pragma unroll
  for (int rt = 0; rt < 4; ++rt)
    #pragma unroll
    for (int t = 0; t < 4; ++t) acc[rt][t] = (f32x4){0.f, 0.f, 0.f, 0.f};

  #pragma unroll
  for (int kk = 0; kk < 4; ++kk){
    const float* xr = X + (size_t)myrow * INC + kk * 32 + quad * 8;
    float4 va = *(const float4*)xr;
    float4 vb = *(const float4*)(xr + 4);
    bf16x8 bh[4], bl[4];
    #pragma unroll
    for (int t = 0; t < 4; ++t){
      size_t bo = (size_t)colg[t] * INC + kk * 32 + quad * 8;
      bh[t] = *(const bf16x8*)(Wthi + bo);
      bl[t] = *(const bf16x8*)(Wtlo + bo);
    }
    bf16x8 ah1, al1;
    split8(va, vb, ah1, al1);                    // ONE split per wave per kk
    if (kk) __syncthreads();
    *(bf16x8*)&shi[w * 16 + l15][quad * 8] = ah1;
    *(bf16x8*)&slo[w * 16 + l15][quad * 8] = al1;
    __syncthreads();
    bf16x8 ah[4], al[4];
    #pragma unroll
    for (int rt = 0; rt < 4; ++rt){
      ah[rt] = *(const bf16x8*)&shi[rt * 16 + l15][quad * 8];
      al[rt] = *(const bf16x8*)&slo[rt * 16 + l15][quad * 8];
    }
    #pragma unroll
    for (int rt = 0; rt < 4; ++rt){
      #pragma unroll
      for (int t = 0; t < 4; ++t){
        acc[rt][t] = __builtin_amdgcn_mfma_f32_16x16x32_bf16(ah[rt], bh[t], acc[rt][t], 0, 0, 0);
        acc[rt][t] = __builtin_amdgcn_mfma_f32_16x16x32_bf16(ah[rt], bl[t], acc[rt][t], 0, 0, 0);
        acc[rt][t] = __builtin_amdgcn_mfma_f32_16x16x32_bf16(al[rt], bh[t], acc[rt][t], 0, 0, 0);
      }
    }
  }

  // store XPh (bf16). C/D layout: col=l15, row=quad*4+r
  #pragma unroll
  for (int rt = 0; rt < 4; ++rt){
    if (!rv[rt]) continue;
    #pragma unroll
    for (int t = 0; t < 4; ++t){
      #pragma unroll
      for (int r = 0; r < 4; ++r){
        XPh[(size_t)(m0 + rt * 16 + quad * 4 + r) * HC + colg[t]] = f2bf(acc[rt][t][r]);
      }
    }
  }

  // epilogue: head-w logits for the 64 rows
  float as[4], ad[4];
  #pragma unroll
  for (int t = 0; t < 4; ++t){
    as[t] = att_src[colg[t]];
    ad[t] = att_dst[colg[t]];
  }
  #pragma unroll
  for (int rt = 0; rt < 4; ++rt){
    if (!rv[rt]) continue;
    float ps[4], pd[4];
    #pragma unroll
    for (int r = 0; r < 4; ++r){
      ps[r] = acc[rt][0][r] * as[0] + acc[rt][1][r] * as[1]
            + acc[rt][2][r] * as[2] + acc[rt][3][r] * as[3];
      pd[r] = acc[rt][0][r] * ad[0] + acc[rt][1][r] * ad[1]
            + acc[rt][2][r] * ad[2] + acc[rt][3][r] * ad[3];
    }
    #pragma unroll
    for (int msk = 1; msk < 16; msk <<= 1){
      #pragma unroll
      for (int r = 0; r < 4; ++r){
        ps[r] += __shfl_xor(ps[r], msk, 64);
        pd[r] += __shfl_xor(pd[r], msk, 64);
      }
    }
    if (l15 == 0){
      #pragma unroll
      for (int r = 0; r < 4; ++r){
        int n = m0 + rt * 16 + quad * 4 + r;
        a_src[n * HEADS + w] = ps[r];
        a_dst[n * HEADS + w] = pd[r];
      }
    }
  }
}

// ---- scatter; reconstructs cross-chunk prefix from bsum (49-entry wave scan) ----
__global__ __launch_bounds__(256) void k_scatter(const int2* __restrict__ sd,
                          const int* __restrict__ pos, const int* __restrict__ rowstart,
                          const int* __restrict__ bsum, int* __restrict__ csr,
                          int E, int nb){
  __shared__ int bps[65];                      // bps[c] = exclusive prefix of bsum at c
  int t = threadIdx.x;
  if (t < 64){
    int v = (t < nb) ? bsum[t] : 0;
    #pragma unroll
    for (int off = 1; off < 64; off <<= 1){
      int u = __shfl_up(v, off, 64);
      if (t >= off) v += u;
    }
    bps[t + 1] = v;
    if (t == 0) bps[0] = 0;
  }
  __syncthreads();
  int e = blockIdx.x * 256 + t;
  if (e < E){
    int2 p = sd[e];
    csr[rowstart[p.y] + bps[p.y >> 10] + pos[e]] = p.x;
  }
}

// ---- fused softmax-coef + gather: wave = node (all 4 heads) ----
__global__ __launch_bounds__(256) void k_fused(const unsigned short* __restrict__ XPh,
    const float* __restrict__ a_src, const float* __restrict__ a_dst,
    const int* __restrict__ rowstart, const int* __restrict__ bsum,
    const int* __restrict__ csr, const float* __restrict__ bias,
    float* __restrict__ out, int N, int nb){
  __shared__ float sh[4][64][4];               // [wave][slot][head]
  __shared__ int bps[65];
  int w = threadIdx.x >> 6, lane = threadIdx.x & 63;
  if (threadIdx.x < 64){
    int v = (threadIdx.x < nb) ? bsum[threadIdx.x] : 0;
    #pragma unroll
    for (int off = 1; off < 64; off <<= 1){
      int u = __shfl_up(v, off, 64);
      if (threadIdx.x >= off) v += u;
    }
    bps[threadIdx.x + 1] = v;
    if (threadIdx.x == 0) bps[0] = 0;
  }
  __syncthreads();

  int n = blockIdx.x * 4 + w;
  bool alive = (n < N);
  if (!alive) n = 0;
  int r0 = rowstart[n] + bps[n >> 10];
  int r1 = rowstart[n + 1] + bps[(n + 1) >> 10];
  int deg = r1 - r0;
  int total = deg + 1;
  int h = lane >> 4;
  float4 ad4 = *(const float4*)&a_dst[n * HEADS];
  bool fast = (total <= 64);
  int jv = n;
  float msel = 0.f, inv_sel = 0.f;

  if (fast){
    if (lane < deg) jv = csr[r0 + lane];
    float l0 = -1e30f, l1 = -1e30f, l2 = -1e30f, l3 = -1e30f;
    if (lane < total){
      float4 a4 = *(const float4*)&a_src[jv * HEADS];
      l0 = a4.x + ad4.x; l0 = (l0 > 0.f) ? l0 : NEG * l0;
      l1 = a4.y + ad4.y; l1 = (l1 > 0.f) ? l1 : NEG * l1;
      l2 = a4.z + ad4.z; l2 = (l2 > 0.f) ? l2 : NEG * l2;
      l3 = a4.w + ad4.w; l3 = (l3 > 0.f) ? l3 : NEG * l3;
    }
    float p0 = __expf(l0), p1 = __expf(l1), p2 = __expf(l2), p3 = __expf(l3);
    float s0 = p0, s1 = p1, s2 = p2, s3 = p3;
    #pragma unroll
    for (int msk = 32; msk; msk >>= 1){
      s0 += __shfl_xor(s0, msk, 64);
      s1 += __shfl_xor(s1, msk, 64);
      s2 += __shfl_xor(s2, msk, 64);
      s3 += __shfl_xor(s3, msk, 64);
    }
    if (lane < total){
      sh[w][lane][0] = p0 / s0;
      sh[w][lane][1] = p1 / s1;
      sh[w][lane][2] = p2 / s2;
      sh[w][lane][3] = p3 / s3;
    }
  } else {
    float m[4] = {-1e30f, -1e30f, -1e30f, -1e30f};
    float s[4] = {0.f, 0.f, 0.f, 0.f};
    float adArr[4] = {ad4.x, ad4.y, ad4.z, ad4.w};
    for (int e = lane; e < total; e += 64){
      int j = (e < deg) ? csr[r0 + e] : n;
      float4 a4 = *(const float4*)&a_src[j * HEADS];
      float aa[4] = {a4.x, a4.y, a4.z, a4.w};
      #pragma unroll
      for (int hh = 0; hh < 4; ++hh){
        float l = aa[hh] + adArr[hh];
        l = (l > 0.f) ? l : NEG * l;
        if (l > m[hh]){ s[hh] = s[hh] * __expf(m[hh] - l) + 1.f; m[hh] = l; }
        else            s[hh] += __expf(l - m[hh]);
      }
    }
    #pragma unroll
    for (int hh = 0; hh < 4; ++hh){
      float mm = m[hh], ss = s[hh];
      #pragma unroll
      for (int msk = 32; msk; msk >>= 1){
        float m2 = __shfl_xor(mm, msk, 64);
        float s2 = __shfl_xor(ss, msk, 64);
        float M = fmaxf(mm, m2);
        float ns = 0.f;
        if (mm > -1e29f) ns += ss * __expf(mm - M);
        if (m2 > -1e29f) ns += s2 * __expf(m2 - M);
        mm = M; ss = ns;
      }
      m[hh] = mm; s[hh] = ss;
    }
    msel    = (h == 0) ? m[0] : (h == 1) ? m[1] : (h == 2) ? m[2] : m[3];
    inv_sel = 1.f / ((h == 0) ? s[0] : (h == 1) ? s[1] : (h == 2) ? s[2] : s[3]);
  }

  float a0 = 0.f, a1 = 0.f, a2 = 0.f, a3 = 0.f;
  const unsigned short* xb = XPh + lane * 4;
  if (fast){
    int e = 0;
    for (; e + 8 <= total; e += 8){
      int jj[8]; float cf[8]; ushort4 xv[8];
      #pragma unroll
      for (int q = 0; q < 8; ++q){
        jj[q] = __builtin_amdgcn_readlane(jv, e + q);
        cf[q] = sh[w][e + q][h];
      }
      #pragma unroll
      for (int q = 0; q < 8; ++q) xv[q] = *(const ushort4*)(xb + (size_t)jj[q] * HC);
      #pragma unroll
      for (int q = 0; q < 8; ++q){
        a0 += cf[q] * bf2f(xv[q].x); a1 += cf[q] * bf2f(xv[q].y);
        a2 += cf[q] * bf2f(xv[q].z); a3 += cf[q] * bf2f(xv[q].w);
      }
    }
    for (; e < total; ++e){
      int j = __builtin_amdgcn_readlane(jv, e);
      float c = sh[w][e][h];
      ushort4 xv = *(const ushort4*)(xb + (size_t)j * HC);
      a0 += c * bf2f(xv.x); a1 += c * bf2f(xv.y); a2 += c * bf2f(xv.z); a3 += c * bf2f(xv.w);
    }
  } else {
    float adh = (h == 0) ? ad4.x : (h == 1) ? ad4.y : (h == 2) ? ad4.z : ad4.w;
    for (int e = 0; e < total; ++e){
      int j = (e < deg) ? csr[r0 + e] : n;
      float4 a4 = *(const float4*)&a_src[j * HEADS];
      float ah = (h == 0) ? a4.x : (h == 1) ? a4.y : (h == 2) ? a4.z : a4.w;
      float l = ah + adh;
      l = (l > 0.f) ? l : NEG * l;
      float c = __expf(l - msel) * inv_sel;
      ushort4 xv = *(const ushort4*)(xb + (size_t)j * HC);
      a0 += c * bf2f(xv.x); a1 += c * bf2f(xv.y); a2 += c * bf2f(xv.z); a3 += c * bf2f(xv.w);
    }
  }
  if (alive){
    float4 b4 = *(const float4*)&bias[lane * 4];
    f32x4 r;
    r[0] = a0 + b4.x; r[1] = a1 + b4.y; r[2] = a2 + b4.z; r[3] = a3 + b4.w;
    __builtin_nontemporal_store(r, (f32x4*)&out[(size_t)n * HC + lane * 4]);
  }
}

extern "C" void kernel_launch(void* const* d_in, const int* in_sizes, int n_in,
                              void* d_out, int out_size, void* d_ws, size_t ws_size,
                              hipStream_t stream){
  const float* x       = (const float*)d_in[0];
  const float* W       = (const float*)d_in[1];
  const float* att_src = (const float*)d_in[2];
  const float* att_dst = (const float*)d_in[3];
  const float* bias    = (const float*)d_in[4];
  const int*   ei      = (const int*)d_in[5];
  int N = in_sizes[0] / INC;     // 50000
  int E = in_sizes[5] / 2;       // 800000

  char* p = (char*)d_ws;
  auto alloc = [&](size_t bytes)->char*{
    char* r = p; p += (bytes + 255) & ~(size_t)255; return r;
  };
  unsigned short* Wthi = (unsigned short*)alloc((size_t)INC * HC * 2);
  unsigned short* Wtlo = (unsigned short*)alloc((size_t)INC * HC * 2);
  unsigned short* XPh  = (unsigned short*)alloc((size_t)N * HC * 2);
  float* aSrc          = (float*)alloc((size_t)N * HEADS * 4);
  float* aDst          = (float*)alloc((size_t)N * HEADS * 4);
  int* deg             = (int*)alloc((size_t)N * 4);
  int* rowstart        = (int*)alloc(((size_t)N + 1) * 4);
  int2* sd             = (int2*)alloc((size_t)E * 8);
  int* pos             = (int*)alloc((size_t)E * 4);
  int* csr             = (int*)alloc((size_t)E * 4);
  int* bsum            = (int*)alloc(256 * 4);

  int GB = (N + 63) / 64;        // 782 gemm blocks
  int EB = (E + 255) / 256;      // 3125 edge blocks
  int nb = (N + 1023) / 1024;    // 49 scan chunks

  hipMemsetAsync(deg, 0, (size_t)N * 4, stream);
  k_pre<<<SPLITB + EB, 256, 0, stream>>>(W, Wthi, Wtlo, ei, sd, pos, deg, E);
  k_gemm_scan<<<GB + nb, 256, 0, stream>>>(x, Wthi, Wtlo, att_src, att_dst,
                                           XPh, aSrc, aDst, deg, rowstart, bsum,
                                           N, GB, nb);
  k_scatter<<<EB, 256, 0, stream>>>(sd, pos, rowstart, bsum, csr, E, nb);
  k_fused<<<(N + 3) / 4, 256, 0, stream>>>(XPh, aSrc, aDst, rowstart, bsum, csr,
                                           bias, (float*)d_out, N, nb);
}